// Round 2
// baseline (4734.384 us; speedup 1.0000x reference)
//
#include <hip/hip_runtime.h>
#include <hip/hip_cooperative_groups.h>

namespace cg = cooperative_groups;

typedef _Float16 f16;
typedef _Float16 half8 __attribute__((ext_vector_type(8)));
typedef _Float16 half4v __attribute__((ext_vector_type(4)));
typedef float f32x4 __attribute__((ext_vector_type(4)));

// x: [128][512][128] f32, alpha: [128] f32, A: [128][128][128] f32 (i,j,k), Omega: [128][32] f32
// out: [128][32] f32
// Phase 1: B[q][i][k] = sum_j A[i][j][k] * x[n(q), t(q), j]  (fp16 store, fp32 acc)
// Phase 2: h <- B_t^T h sequentially, fp32.
// NEW this round: ONE persistent cooperative kernel (512 blocks = exactly 2/CU,
// co-residency guaranteed by hipLaunchCooperativeKernel). grid.sync() replaces the
// 33 dispatch boundaries (~10 µs each -> ~3 µs each). __threadfence() before each
// sync gives device-scope release (L2 writeback) for cross-XCD B visibility.
// Fallback to the verified multi-dispatch path if cooperative launch is rejected.

// ---------- prologue cvt: A (full, transposed) + X slice t<16 (fallback path) ----
__global__ void k_cvt_pre(const float* __restrict__ x, f16* __restrict__ Xh,
                          const float* __restrict__ A, f16* __restrict__ Af2) {
    int b = blockIdx.x;
    if (b < 256) {
        int tid = (b << 8) + threadIdx.x;       // [0, 65536) float4s, t<16 for all n
        int n = tid >> 9;
        int rem = tid & 511;                    // t*32 + j/4, t<16
        int off = (n << 16) + (rem << 2);       // float offset
        float4 v = *(const float4*)(x + off);
        half4v o; o[0] = (f16)v.x; o[1] = (f16)v.y; o[2] = (f16)v.z; o[3] = (f16)v.w;
        *(half4v*)(Xh + off) = o;
    } else {
        int o = ((b - 256) << 8) + threadIdx.x; // [0, 2M): Af2[i][k][j] = A[i][j][k]
        int i = o >> 14, k = (o >> 7) & 127, j = o & 127;
        Af2[o] = (f16)A[(i << 14) + (j << 7) + k];
    }
}

// ================= gemm body (R2 structure, VGPR-lean: no reg prefetch) ============
// block: fixed i, 128-q tile. M=k=128, N=q=128, K=j=128. lA/lX are 32 KB each.
__device__ __forceinline__
void gemm_body(f16* lA, f16* lX, const f16* __restrict__ Af2, const f16* __restrict__ Xh,
               f16* __restrict__ B, int t0, int logTc, int qtile, int i, int tid) {
    const int row = tid >> 4;
    const int ch = tid & 15;
    const int Tcm1 = (1 << logTc) - 1;

    {
        const f16* srcA = Af2 + ((size_t)i << 14);
#pragma unroll
        for (int r = 0; r < 128; r += 16) {
            int rr = row + r;
            uint4 v = *(const uint4*)(srcA + (rr << 7) + (ch << 3));
            *(uint4*)(&lA[(rr << 7) + ((ch ^ (rr & 15)) << 3)]) = v;
        }
#pragma unroll
        for (int r = 0; r < 128; r += 16) {
            int rr = row + r;
            int qr = (qtile << 7) + rr;
            int n = qr >> logTc;
            int trel = qr & Tcm1;
            const f16* srcX = Xh + (((size_t)(n << 9) + t0 + trel) << 7);
            uint4 v = *(const uint4*)(srcX + (ch << 3));
            *(uint4*)(&lX[(rr << 7) + ((ch ^ (rr & 15)) << 3)]) = v;
        }
    }
    __syncthreads();

    const int wave = tid >> 6;
    const int lane = tid & 63;
    const int l15 = lane & 15;
    const int l4 = lane >> 4;
    f32x4 acc[8][2] = {};

#pragma unroll
    for (int ks = 0; ks < 4; ++ks) {
        const int c = (ks << 2) + l4;
        half8 afr[8], bfr[2];
#pragma unroll
        for (int mt = 0; mt < 8; ++mt) {
            int rowA = (mt << 4) + l15;
            afr[mt] = *(const half8*)(&lA[(rowA << 7) + ((c ^ l15) << 3)]);
        }
#pragma unroll
        for (int qt = 0; qt < 2; ++qt) {
            int rowX = (wave << 5) + (qt << 4) + l15;
            bfr[qt] = *(const half8*)(&lX[(rowX << 7) + ((c ^ l15) << 3)]);
        }
#pragma unroll
        for (int mt = 0; mt < 8; ++mt)
#pragma unroll
            for (int qt = 0; qt < 2; ++qt)
                acc[mt][qt] = __builtin_amdgcn_mfma_f32_16x16x32_f16(
                    afr[mt], bfr[qt], acc[mt][qt], 0, 0, 0);
    }

    // epilogue: stage C tile in lA (XOR-swizzled), then coalesced dwordx4 stores
    __syncthreads();
    f16* stage = lA;
#pragma unroll
    for (int mt = 0; mt < 8; ++mt)
#pragma unroll
        for (int qt = 0; qt < 2; ++qt) {
            int q = (wave << 5) + (qt << 4) + l15;          // q & 15 == l15
            int chunk = (mt << 1) + (l4 >> 1);
            int hf = l4 & 1;
            half4v o;
            o[0] = (f16)acc[mt][qt][0];
            o[1] = (f16)acc[mt][qt][1];
            o[2] = (f16)acc[mt][qt][2];
            o[3] = (f16)acc[mt][qt][3];
            *(half4v*)(&stage[(q << 7) + (((chunk ^ l15) << 3) + (hf << 2))]) = o;
        }
    __syncthreads();
    {
        const int lr = lane >> 4;
        const int lc = lane & 15;
#pragma unroll
        for (int it = 0; it < 8; ++it) {
            int q = (wave << 5) + (it << 2) + lr;
            uint4 v = *(const uint4*)(&stage[(q << 7) + ((lc ^ (q & 15)) << 3)]);
            size_t qg = (size_t)((qtile << 7) + q);
            *(uint4*)(B + (qg << 14) + (i << 7) + (lc << 3)) = v;
        }
    }
}

// ================= chain body (R2 structure, depth-4 reg prefetch) =================
__device__ __forceinline__
void chain_body(float* hl, float (*part)[132], const f16* __restrict__ B,
                float* __restrict__ hstate, const float* __restrict__ alpha,
                const float* __restrict__ Om, float* __restrict__ out,
                int Tc, int first, int last, int n, int tid) {
    const int kg = tid & 15;
    const int iq = tid >> 4;

    if (tid < 128) hl[tid] = first ? alpha[tid] : hstate[(n << 7) + tid];
    __syncthreads();

    const f16* bbase = B + (((size_t)n * Tc) << 14) + (iq << 10) + (kg << 3);
    half8 buf[4][8];
#pragma unroll
    for (int s = 0; s < 4; ++s)
#pragma unroll
        for (int ii = 0; ii < 8; ++ii)
            buf[s][ii] = *(const half8*)(bbase + ((size_t)s << 14) + (ii << 7));

    for (int t = 0; t < Tc; t += 4) {
#pragma unroll
        for (int s = 0; s < 4; ++s) {
            float4 h0 = *(const float4*)&hl[iq << 3];
            float4 h1 = *(const float4*)&hl[(iq << 3) + 4];
            float acc[8] = {0, 0, 0, 0, 0, 0, 0, 0};
#pragma unroll
            for (int ii = 0; ii < 4; ++ii) {
                float hv = (&h0.x)[ii];
#pragma unroll
                for (int j = 0; j < 8; ++j)
                    acc[j] += hv * (float)buf[s][ii][j];
            }
#pragma unroll
            for (int ii = 0; ii < 4; ++ii) {
                float hv = (&h1.x)[ii];
#pragma unroll
                for (int j = 0; j < 8; ++j)
                    acc[j] += hv * (float)buf[s][ii + 4][j];
            }
            int tn = t + s + 4;
            if (tn < Tc) {
#pragma unroll
                for (int ii = 0; ii < 8; ++ii)
                    buf[s][ii] = *(const half8*)(bbase + ((size_t)tn << 14) + (ii << 7));
            }
            *(float4*)(&part[iq][kg << 3])       = make_float4(acc[0], acc[1], acc[2], acc[3]);
            *(float4*)(&part[iq][(kg << 3) + 4]) = make_float4(acc[4], acc[5], acc[6], acc[7]);
            __syncthreads();
            if (tid < 128) {
                float s0 = part[0][tid] + part[1][tid];
                float s1 = part[2][tid] + part[3][tid];
                float s2 = part[4][tid] + part[5][tid];
                float s3 = part[6][tid] + part[7][tid];
                s0 += part[8][tid] + part[9][tid];
                s1 += part[10][tid] + part[11][tid];
                s2 += part[12][tid] + part[13][tid];
                s3 += part[14][tid] + part[15][tid];
                hl[tid] = (s0 + s1) + (s2 + s3);
            }
            __syncthreads();
        }
    }

    if (!last) {
        if (tid < 128) hstate[(n << 7) + tid] = hl[tid];
    } else if (tid < 32) {
        float s = 0.f;
        for (int i2 = 0; i2 < 128; ++i2) s += hl[i2] * Om[(i2 << 5) + tid];
        out[(n << 5) + tid] = s;
    }
}

// chain block -> n remap (Tc=16): consumer lands with bx%8 == qtile%8 == producer's.
__device__ __forceinline__ int chain_n(int bx, int logTc) {
    if (logTc == 4) return (bx & 64) | ((bx & 7) << 3) | ((bx >> 3) & 7);
    return bx;
}

// ================= persistent cooperative kernel (Tc=16 fixed) =================
// 512 blocks x 256 threads, 2 blocks/CU (LDS 64KB). 33 grid.sync()s total.
__global__ __launch_bounds__(256, 2)
void k_persist(const float* __restrict__ x, const float* __restrict__ alpha,
               const float* __restrict__ A, const float* __restrict__ Om,
               float* __restrict__ out,
               f16* __restrict__ Af2, f16* __restrict__ Xh,
               f16* __restrict__ B0, f16* __restrict__ B1,
               float* __restrict__ hstate) {
    __shared__ __align__(16) char smem[65536];
    cg::grid_group grid = cg::this_grid();
    const int bx = blockIdx.x;
    const int tid = threadIdx.x;
    const int gtid = (bx << 8) + tid;          // 131072 threads

    // ---- P0: convert X (2M float4) and A (2M scalars, transposed) ----
#pragma unroll
    for (int it = 0; it < 16; ++it) {
        int f = gtid + (it << 17);
        float4 v = ((const float4*)x)[f];
        half4v o; o[0] = (f16)v.x; o[1] = (f16)v.y; o[2] = (f16)v.z; o[3] = (f16)v.w;
        ((half4v*)Xh)[f] = o;
    }
#pragma unroll
    for (int it = 0; it < 16; ++it) {
        int o = gtid + (it << 17);
        int i = o >> 14, k = (o >> 7) & 127, j = o & 127;
        Af2[o] = (f16)A[(i << 14) + (j << 7) + k];
    }
    __threadfence();
    grid.sync();

    // ---- P1: gemm chunk 0 (2048 jobs over 512 blocks, 4 each) ----
    for (int it = 0; it < 4; ++it) {
        int job = bx + (it << 9);
        gemm_body((f16*)smem, (f16*)(smem + 32768), Af2, Xh, B0,
                  0, 4, job & 15, job >> 4, tid);
        __syncthreads();
    }
    __threadfence();
    grid.sync();

    // ---- main loop: chunk c chain + chunk c+1 gemm, one grid.sync per chunk ----
    for (int c = 0; c < 32; ++c) {
        f16* Br = (c & 1) ? B1 : B0;
        f16* Bw = (c & 1) ? B0 : B1;
        if (bx < 128) {
            chain_body((float*)smem, (float(*)[132])(smem + 512), Br, hstate,
                       alpha, Om, out, 16, c == 0, c == 31, chain_n(bx, 4), tid);
            if (c + 1 < 32) {
                __syncthreads();               // hl reads done before gemm clobbers smem
                int job = 1920 + bx;           // qtile = bx&15 -> producer XCD matches too
                gemm_body((f16*)smem, (f16*)(smem + 32768), Af2, Xh, Bw,
                          (c + 1) << 4, 4, job & 15, job >> 4, tid);
            }
        } else if (c + 1 < 32) {
            int w = bx - 128;
            for (int it = 0; it < 5; ++it) {
                int job = w + it * 384;        // qtile = w&15 for every it (384%16==0)
                gemm_body((f16*)smem, (f16*)(smem + 32768), Af2, Xh, Bw,
                          (c + 1) << 4, 4, job & 15, job >> 4, tid);
                __syncthreads();
            }
        }
        if (c + 1 < 32) { __threadfence(); grid.sync(); }
    }
}

// ================= fallback multi-dispatch kernels (verified round-1 path) ========
__global__ __launch_bounds__(256, 2)
void k_gemm0(const f16* __restrict__ Af2, const f16* __restrict__ Xh,
             f16* __restrict__ B, const float* __restrict__ x, int logTc) {
    __shared__ __align__(16) char smem[65536];
    const int bx = blockIdx.x;
    const int Tc = 1 << logTc;
    const int ngemm = Tc << 7;
    if (bx < ngemm) {
        gemm_body((f16*)smem, (f16*)(smem + 32768), Af2, Xh, B, 0, logTc,
                  bx & (Tc - 1), bx >> logTc, threadIdx.x);
    } else {
        int f = ((bx - ngemm) << 8) + threadIdx.x;
        int t = (f & 16383) >> 5;
        if (t < 16) return;
        float4 v = *(const float4*)(x + ((size_t)f << 2));
        half4v o; o[0] = (f16)v.x; o[1] = (f16)v.y; o[2] = (f16)v.z; o[3] = (f16)v.w;
        *(half4v*)(Xh + ((size_t)f << 2)) = o;
    }
}

__global__ __launch_bounds__(256, 2)
void k_chain(const f16* __restrict__ B, float* __restrict__ hstate,
             const float* __restrict__ alpha, const float* __restrict__ Om,
             float* __restrict__ out, int Tc, int logTc, int first, int last) {
    __shared__ __align__(16) char smem[16384];
    chain_body((float*)smem, (float(*)[132])(smem + 512), B, hstate, alpha, Om, out,
               Tc, first, last, chain_n(blockIdx.x, logTc), threadIdx.x);
}

__global__ __launch_bounds__(256, 2)
void k_fused(const f16* __restrict__ Af2, const f16* __restrict__ Xh,
             f16* __restrict__ Bw, const f16* __restrict__ Br,
             float* __restrict__ hstate, const float* __restrict__ alpha,
             const float* __restrict__ Om, float* __restrict__ out,
             int t0g, int logTc, int Tc, int first, int last) {
    __shared__ __align__(16) char smem[65536];
    const int bx = blockIdx.x;
    if (bx < 128) {
        chain_body((float*)smem, (float(*)[132])(smem + 512), Br, hstate, alpha, Om, out,
                   Tc, first, last, chain_n(bx, logTc), threadIdx.x);
    } else {
        int g = bx - 128;
        int qtile = g & (Tc - 1);
        int i = g >> logTc;
        gemm_body((f16*)smem, (f16*)(smem + 32768), Af2, Xh, Bw, t0g, logTc,
                  qtile, i, threadIdx.x);
    }
}

extern "C" void kernel_launch(void* const* d_in, const int* in_sizes, int n_in,
                              void* d_out, int out_size, void* d_ws, size_t ws_size,
                              hipStream_t stream) {
    const float* x     = (const float*)d_in[0];
    const float* alpha = (const float*)d_in[1];
    const float* A     = (const float*)d_in[2];
    const float* Om    = (const float*)d_in[3];
    float* out = (float*)d_out;

    char* ws = (char*)d_ws;
    f16*   Af2    = (f16*)ws;                          // 4 MB  [i][k][j]
    f16*   Xh     = (f16*)(ws + ((size_t)4 << 20));    // 16 MB [n*512+t][j]
    float* hstate = (float*)(ws + ((size_t)20 << 20)); // 64 KB

    // persistent path needs Tc=16 double buffers: 21 MB + 2*64 MB
    bool persist_ok = ((size_t)21 << 20) + (((size_t)16 << 22) * 2) <= ws_size;

    if (persist_ok) {
        f16* B0 = (f16*)(ws + ((size_t)21 << 20));
        f16* B1 = (f16*)(ws + ((size_t)21 << 20) + ((size_t)16 << 22));
        void* args[] = { (void*)&x, (void*)&alpha, (void*)&A, (void*)&Om, (void*)&out,
                         (void*)&Af2, (void*)&Xh, (void*)&B0, (void*)&B1, (void*)&hstate };
        hipError_t e = hipLaunchCooperativeKernel((const void*)k_persist, dim3(512),
                                                  dim3(256), args, 0, stream);
        if (e == hipSuccess) { (void)in_sizes; (void)n_in; (void)out_size; return; }
        // else fall through to multi-dispatch path
    }

    int Tc = 16;
    while (Tc > 4 && ((size_t)21 << 20) + (((size_t)Tc << 22) * 2) > ws_size) Tc >>= 1;
    int logTc = 31 - __builtin_clz(Tc);
    int nch = 512 / Tc;
    f16* Bc[2];
    Bc[0] = (f16*)(ws + ((size_t)21 << 20));
    Bc[1] = (f16*)(ws + ((size_t)21 << 20) + ((size_t)Tc << 22));

    k_cvt_pre<<<256 + 8192, 256, 0, stream>>>(x, Xh, A, Af2);
    k_gemm0<<<(Tc << 7) + 8192, 256, 0, stream>>>(Af2, Xh, Bc[0], x, logTc);

    for (int c = 0; c < nch; ++c) {
        const f16* br = Bc[c & 1];
        if (c + 1 < nch) {
            k_fused<<<128 + Tc * 128, 256, 0, stream>>>(
                Af2, Xh, Bc[(c + 1) & 1], br, hstate, alpha, Om, out,
                (c + 1) * Tc, logTc, Tc, c == 0, c == nch - 1);
        } else {
            k_chain<<<128, 256, 0, stream>>>(br, hstate, alpha, Om, out,
                                             Tc, logTc, c == 0, c == nch - 1);
        }
    }
    (void)in_sizes; (void)n_in; (void)out_size;
}

// Round 3
// 964.727 us; speedup vs baseline: 4.9075x; 4.9075x over previous
//
#include <hip/hip_runtime.h>

typedef _Float16 f16;
typedef _Float16 half8 __attribute__((ext_vector_type(8)));
typedef _Float16 half4v __attribute__((ext_vector_type(4)));
typedef float f32x4 __attribute__((ext_vector_type(4)));

// x: [128][512][128] f32, alpha: [128] f32, A: [128][128][128] f32 (i,j,k), Omega: [128][32] f32
// out: [128][32] f32
// Phase 1: B[q][i][k] = sum_j A[i][j][k] * x[n(q), t(q), j]  (fp16 store, fp32 acc)
// Phase 2: h <- B_t^T h sequentially, fp32.
// Pipeline: dispatch D_c = chain(c) [blocks 0..127] + gemm(c+1) [blocks 128..]; stream
// order between dispatches is the only synchronization.
// R2 LESSON: cooperative grid.sync() is ~5x worse than dispatch boundaries on gfx950
// (its acquire/release fences invalidate/writeback per-XCD L2). Multi-dispatch kept.
// NEW this round: gemm staging via width-16 global_load_lds (async DMA, no VGPR
// round trip). LDS dest is linear (wave-uniform base + lane*16, per HW requirement);
// the XOR bank-swizzle is applied on the per-lane GLOBAL source address instead
// (src_chunk = chunk ^ (row&15), bijective per row) so the MFMA-phase swizzled
// ds_read_b128 pattern is unchanged.

#define GLOAD_LDS16(g, l) __builtin_amdgcn_global_load_lds( \
    (const __attribute__((address_space(1))) void*)(g),     \
    (__attribute__((address_space(3))) void*)(l), 16, 0, 0)

// ---------- prologue cvt: A (full, transposed) + X slice t<16 ----------
__global__ void k_cvt_pre(const float* __restrict__ x, f16* __restrict__ Xh,
                          const float* __restrict__ A, f16* __restrict__ Af2) {
    int b = blockIdx.x;
    if (b < 256) {
        int tid = (b << 8) + threadIdx.x;       // [0, 65536) float4s, t<16 for all n
        int n = tid >> 9;
        int rem = tid & 511;                    // t*32 + j/4, t<16
        int off = (n << 16) + (rem << 2);       // float offset
        float4 v = *(const float4*)(x + off);
        half4v o; o[0] = (f16)v.x; o[1] = (f16)v.y; o[2] = (f16)v.z; o[3] = (f16)v.w;
        *(half4v*)(Xh + off) = o;
    } else {
        int o = ((b - 256) << 8) + threadIdx.x; // [0, 2M): Af2[i][k][j] = A[i][j][k]
        int i = o >> 14, k = (o >> 7) & 127, j = o & 127;
        Af2[o] = (f16)A[(i << 14) + (j << 7) + k];
    }
}

// ================= gemm body =================
// block: fixed i, 128-q tile. M=k=128, N=q=128, K=j=128. lA/lX are 32 KB each.
__device__ __forceinline__
void gemm_body(f16* lA, f16* lX, const f16* __restrict__ Af2, const f16* __restrict__ Xh,
               f16* __restrict__ B, int t0, int logTc, int qtile, int i, int tid) {
    const int Tcm1 = (1 << logTc) - 1;
    const int rowidx = tid >> 4;        // 0..15 == (dest row) & 15
    const int cc = tid & 15;            // dest 16B-chunk within row
    const int scc = cc ^ rowidx;        // swizzled SOURCE chunk (rule #21)
    const int wv = tid >> 6;            // wave id, LDS base must be wave-uniform

    {
        const f16* srcA = Af2 + ((size_t)i << 14);
#pragma unroll
        for (int r = 0; r < 128; r += 16) {
            GLOAD_LDS16(srcA + ((r + rowidx) << 7) + (scc << 3),
                        lA + ((r + (wv << 2)) << 7));
        }
#pragma unroll
        for (int r = 0; r < 128; r += 16) {
            int qr = (qtile << 7) + r + rowidx;
            int n = qr >> logTc;
            int trel = qr & Tcm1;
            GLOAD_LDS16(Xh + (((size_t)(n << 9) + t0 + trel) << 7) + (scc << 3),
                        lX + ((r + (wv << 2)) << 7));
        }
    }
    __syncthreads();   // barrier drain waits vmcnt(0): all 16 DMA loads landed

    const int lane = tid & 63;
    const int l15 = lane & 15;
    const int l4 = lane >> 4;
    f32x4 acc[8][2] = {};

#pragma unroll
    for (int ks = 0; ks < 4; ++ks) {
        const int c = (ks << 2) + l4;
        half8 afr[8], bfr[2];
#pragma unroll
        for (int mt = 0; mt < 8; ++mt) {
            int rowA = (mt << 4) + l15;
            afr[mt] = *(const half8*)(&lA[(rowA << 7) + ((c ^ l15) << 3)]);
        }
#pragma unroll
        for (int qt = 0; qt < 2; ++qt) {
            int rowX = (wv << 5) + (qt << 4) + l15;
            bfr[qt] = *(const half8*)(&lX[(rowX << 7) + ((c ^ l15) << 3)]);
        }
#pragma unroll
        for (int mt = 0; mt < 8; ++mt)
#pragma unroll
            for (int qt = 0; qt < 2; ++qt)
                acc[mt][qt] = __builtin_amdgcn_mfma_f32_16x16x32_f16(
                    afr[mt], bfr[qt], acc[mt][qt], 0, 0, 0);
    }

    // epilogue: stage C tile in lA (XOR-swizzled), then coalesced dwordx4 stores
    __syncthreads();
    f16* stage = lA;
#pragma unroll
    for (int mt = 0; mt < 8; ++mt)
#pragma unroll
        for (int qt = 0; qt < 2; ++qt) {
            int q = (wv << 5) + (qt << 4) + l15;            // q & 15 == l15
            int chunk = (mt << 1) + (l4 >> 1);
            int hf = l4 & 1;
            half4v o;
            o[0] = (f16)acc[mt][qt][0];
            o[1] = (f16)acc[mt][qt][1];
            o[2] = (f16)acc[mt][qt][2];
            o[3] = (f16)acc[mt][qt][3];
            *(half4v*)(&stage[(q << 7) + (((chunk ^ l15) << 3) + (hf << 2))]) = o;
        }
    __syncthreads();
    {
        const int lr = lane >> 4;
        const int lc = lane & 15;
#pragma unroll
        for (int it = 0; it < 8; ++it) {
            int q = (wv << 5) + (it << 2) + lr;
            uint4 v = *(const uint4*)(&stage[(q << 7) + ((lc ^ (q & 15)) << 3)]);
            size_t qg = (size_t)((qtile << 7) + q);
            *(uint4*)(B + (qg << 14) + (i << 7) + (lc << 3)) = v;
        }
    }
}

// ================= chain body (depth-4 reg prefetch) =================
__device__ __forceinline__
void chain_body(float* hl, float (*part)[132], const f16* __restrict__ B,
                float* __restrict__ hstate, const float* __restrict__ alpha,
                const float* __restrict__ Om, float* __restrict__ out,
                int Tc, int first, int last, int n, int tid) {
    const int kg = tid & 15;
    const int iq = tid >> 4;

    if (tid < 128) hl[tid] = first ? alpha[tid] : hstate[(n << 7) + tid];
    __syncthreads();

    const f16* bbase = B + (((size_t)n * Tc) << 14) + (iq << 10) + (kg << 3);
    half8 buf[4][8];
#pragma unroll
    for (int s = 0; s < 4; ++s)
#pragma unroll
        for (int ii = 0; ii < 8; ++ii)
            buf[s][ii] = *(const half8*)(bbase + ((size_t)s << 14) + (ii << 7));

    for (int t = 0; t < Tc; t += 4) {
#pragma unroll
        for (int s = 0; s < 4; ++s) {
            float4 h0 = *(const float4*)&hl[iq << 3];
            float4 h1 = *(const float4*)&hl[(iq << 3) + 4];
            float acc[8] = {0, 0, 0, 0, 0, 0, 0, 0};
#pragma unroll
            for (int ii = 0; ii < 4; ++ii) {
                float hv = (&h0.x)[ii];
#pragma unroll
                for (int j = 0; j < 8; ++j)
                    acc[j] += hv * (float)buf[s][ii][j];
            }
#pragma unroll
            for (int ii = 0; ii < 4; ++ii) {
                float hv = (&h1.x)[ii];
#pragma unroll
                for (int j = 0; j < 8; ++j)
                    acc[j] += hv * (float)buf[s][ii + 4][j];
            }
            int tn = t + s + 4;
            if (tn < Tc) {
#pragma unroll
                for (int ii = 0; ii < 8; ++ii)
                    buf[s][ii] = *(const half8*)(bbase + ((size_t)tn << 14) + (ii << 7));
            }
            *(float4*)(&part[iq][kg << 3])       = make_float4(acc[0], acc[1], acc[2], acc[3]);
            *(float4*)(&part[iq][(kg << 3) + 4]) = make_float4(acc[4], acc[5], acc[6], acc[7]);
            __syncthreads();
            if (tid < 128) {
                float s0 = part[0][tid] + part[1][tid];
                float s1 = part[2][tid] + part[3][tid];
                float s2 = part[4][tid] + part[5][tid];
                float s3 = part[6][tid] + part[7][tid];
                s0 += part[8][tid] + part[9][tid];
                s1 += part[10][tid] + part[11][tid];
                s2 += part[12][tid] + part[13][tid];
                s3 += part[14][tid] + part[15][tid];
                hl[tid] = (s0 + s1) + (s2 + s3);
            }
            __syncthreads();
        }
    }

    if (!last) {
        if (tid < 128) hstate[(n << 7) + tid] = hl[tid];
    } else if (tid < 32) {
        float s = 0.f;
        for (int i2 = 0; i2 < 128; ++i2) s += hl[i2] * Om[(i2 << 5) + tid];
        out[(n << 5) + tid] = s;
    }
}

// chain block -> n remap (Tc=16): consumer lands with bx%8 == qtile%8 == producer's.
__device__ __forceinline__ int chain_n(int bx, int logTc) {
    if (logTc == 4) return (bx & 64) | ((bx & 7) << 3) | ((bx >> 3) & 7);
    return bx;
}

// ================= kernels =================
// gemm chunk 0 + remaining X conversion (t>=16), overlapped in one dispatch.
__global__ __launch_bounds__(256, 2)
void k_gemm0(const f16* __restrict__ Af2, const f16* __restrict__ Xh,
             f16* __restrict__ B, const float* __restrict__ x, int logTc) {
    __shared__ __align__(16) char smem[65536];
    const int bx = blockIdx.x;
    const int Tc = 1 << logTc;
    const int ngemm = Tc << 7;
    if (bx < ngemm) {
        gemm_body((f16*)smem, (f16*)(smem + 32768), Af2, Xh, B, 0, logTc,
                  bx & (Tc - 1), bx >> logTc, threadIdx.x);
    } else {
        int f = ((bx - ngemm) << 8) + threadIdx.x;   // float4 index [0, 2M)
        int t = (f & 16383) >> 5;                    // 32 float4 per t-row
        if (t < 16) return;                          // done in k_cvt_pre
        float4 v = *(const float4*)(x + ((size_t)f << 2));
        half4v o; o[0] = (f16)v.x; o[1] = (f16)v.y; o[2] = (f16)v.z; o[3] = (f16)v.w;
        *(half4v*)(Xh + ((size_t)f << 2)) = o;
    }
}

__global__ __launch_bounds__(256, 2)
void k_chain(const f16* __restrict__ B, float* __restrict__ hstate,
             const float* __restrict__ alpha, const float* __restrict__ Om,
             float* __restrict__ out, int Tc, int logTc, int first, int last) {
    __shared__ __align__(16) char smem[16384];
    chain_body((float*)smem, (float(*)[132])(smem + 512), B, hstate, alpha, Om, out,
               Tc, first, last, chain_n(blockIdx.x, logTc), threadIdx.x);
}

// fused: blocks 0..127 run chain(c) on Br; blocks 128.. run gemm(c+1) into Bw.
__global__ __launch_bounds__(256, 2)
void k_fused(const f16* __restrict__ Af2, const f16* __restrict__ Xh,
             f16* __restrict__ Bw, const f16* __restrict__ Br,
             float* __restrict__ hstate, const float* __restrict__ alpha,
             const float* __restrict__ Om, float* __restrict__ out,
             int t0g, int logTc, int Tc, int first, int last) {
    __shared__ __align__(16) char smem[65536];
    const int bx = blockIdx.x;
    if (bx < 128) {
        chain_body((float*)smem, (float(*)[132])(smem + 512), Br, hstate, alpha, Om, out,
                   Tc, first, last, chain_n(bx, logTc), threadIdx.x);
    } else {
        int g = bx - 128;
        int qtile = g & (Tc - 1);
        int i = g >> logTc;
        gemm_body((f16*)smem, (f16*)(smem + 32768), Af2, Xh, Bw, t0g, logTc,
                  qtile, i, threadIdx.x);
    }
}

extern "C" void kernel_launch(void* const* d_in, const int* in_sizes, int n_in,
                              void* d_out, int out_size, void* d_ws, size_t ws_size,
                              hipStream_t stream) {
    const float* x     = (const float*)d_in[0];
    const float* alpha = (const float*)d_in[1];
    const float* A     = (const float*)d_in[2];
    const float* Om    = (const float*)d_in[3];
    float* out = (float*)d_out;

    char* ws = (char*)d_ws;
    f16*   Af2    = (f16*)ws;                          // 4 MB  [i][k][j]
    f16*   Xh     = (f16*)(ws + ((size_t)4 << 20));    // 16 MB [n*512+t][j]
    float* hstate = (float*)(ws + ((size_t)20 << 20)); // 64 KB

    int Tc = 16;   // double-buffered: 2 x 64 MB -> LLC resident with X+A
    while (Tc > 4 && ((size_t)21 << 20) + (((size_t)Tc << 22) * 2) > ws_size) Tc >>= 1;
    int logTc = 31 - __builtin_clz(Tc);
    int nch = 512 / Tc;
    f16* Bc[2];
    Bc[0] = (f16*)(ws + ((size_t)21 << 20));
    Bc[1] = (f16*)(ws + ((size_t)21 << 20) + ((size_t)Tc << 22));

    // prologue: cvt A + X[t<16], then gemm chunk 0 overlapped with cvt X[t>=16]
    k_cvt_pre<<<256 + 8192, 256, 0, stream>>>(x, Xh, A, Af2);
    k_gemm0<<<(Tc << 7) + 8192, 256, 0, stream>>>(Af2, Xh, Bc[0], x, logTc);

    for (int c = 0; c < nch; ++c) {
        const f16* br = Bc[c & 1];
        if (c + 1 < nch) {
            // chain(c) + gemm(c+1) overlapped; stream order guarantees gemm(c) done.
            k_fused<<<128 + Tc * 128, 256, 0, stream>>>(
                Af2, Xh, Bc[(c + 1) & 1], br, hstate, alpha, Om, out,
                (c + 1) * Tc, logTc, Tc, c == 0, c == nch - 1);
        } else {
            k_chain<<<128, 256, 0, stream>>>(br, hstate, alpha, Om, out,
                                             Tc, logTc, c == 0, c == nch - 1);
        }
    }
    (void)in_sizes; (void)n_in; (void)out_size;
}